// Round 10
// baseline (99.964 us; speedup 1.0000x reference)
//
#include <hip/hip_runtime.h>
#include <math.h>

#define NPIX   9216        // 96*96
#define PH     96
#define FULL_H 768
#define NC     19
#define IGN    255

#define AFF_ROWS   4                          // one row per wave
#define AFF_BLOCKS (NPIX / AFF_ROWS)          // 2304
#define CE_BLOCKS  ((FULL_H * FULL_H) / 256)  // 2304
#define FUSED_BLOCKS (AFF_BLOCKS + CE_BLOCKS) // 4608

typedef float f4 __attribute__((ext_vector_type(4)));
typedef int   i4 __attribute__((ext_vector_type(4)));

// ws layout (bytes):
//   lab      int[9216]            @ 0
//   aff_part float[AFF_BLOCKS]    @ 36864
//   ce1_part float[CE_BLOCKS]     @ 46080
//   ce2_part float[CE_BLOCKS]     @ 55296
//   ced_part float[CE_BLOCKS]     @ 64512

__device__ __forceinline__ float block_reduce_f(float v, float* sm) {
    #pragma unroll
    for (int o = 32; o > 0; o >>= 1) v += __shfl_down(v, o, 64);
    int lane = threadIdx.x & 63, wid = threadIdx.x >> 6;
    if (lane == 0) sm[wid] = v;
    __syncthreads();
    if (threadIdx.x == 0) v = sm[0] + sm[1] + sm[2] + sm[3];
    return v;  // valid only in thread 0
}

__device__ __forceinline__ double block_reduce_d(double v, double* sm) {
    #pragma unroll
    for (int o = 32; o > 0; o >>= 1) v += __shfl_down(v, o, 64);
    int lane = threadIdx.x & 63, wid = threadIdx.x >> 6;
    if (lane == 0) sm[wid] = v;
    __syncthreads();
    if (threadIdx.x == 0) v = sm[0] + sm[1] + sm[2] + sm[3];
    return v;  // valid only in thread 0
}

__global__ __launch_bounds__(256) void prep_kernel(const int* __restrict__ target,
                                                   int* __restrict__ lab) {
    int i = blockIdx.x * 256 + threadIdx.x;
    if (i < NPIX) {
        int r = i / PH, c = i % PH;   // nearest: src = floor(dst*768/96) = dst*8
        lab[i] = target[(r * 8) * FULL_H + c * 8];
    }
}

__device__ __forceinline__ float aff_term(f4 p, i4 l, int ln) {
    float d0 = p.x - (l.x == ln ? 1.f : 0.f);
    float d1 = p.y - (l.y == ln ? 1.f : 0.f);
    float d2 = p.z - (l.z == ln ? 1.f : 0.f);
    float d3 = p.w - (l.w == ln ? 1.f : 0.f);
    return d0 * d0 + d1 * d1 + d2 * d2 + d3 * d3;
}

// Even blocks: affinity MSE (one row per wave, sequential 4x1KB nt bursts).
// Odd blocks:  weighted-CE tile (256 pixels). ce work hides under the aff
// HBM stream; nt keeps the stream out of the caches ce uses.
__global__ __launch_bounds__(256) void fused_kernel(const float* __restrict__ aff,
                                                    const int* __restrict__ lab,
                                                    const float* __restrict__ lg1,
                                                    const float* __restrict__ lg2,
                                                    const float* __restrict__ cw,
                                                    const int* __restrict__ target,
                                                    float* __restrict__ aff_part,
                                                    float* __restrict__ p1,
                                                    float* __restrict__ p2,
                                                    float* __restrict__ pd) {
    __shared__ float sm[4];
    const int bid = blockIdx.x;

    if ((bid & 1) == 0) {
        // ---------------- affinity MSE: 4 rows (one per wave) ----------------
        const int grp  = bid >> 1;             // 0..2303
        const int tid  = threadIdx.x;
        const int w    = tid >> 6;
        const int lane = tid & 63;
        const int row  = grp * AFF_ROWS + w;
        const int ln   = lab[row];
        const f4* rbase = (const f4*)(aff + (size_t)row * NPIX);
        const i4* ll    = (const i4*)lab;

        float s = 0.f;
        #pragma unroll
        for (int i = 0; i < 9; ++i) {
            const int k = i * 256 + lane;      // f4 index within row
            f4 q0 = __builtin_nontemporal_load(rbase + k + 0 * 64);
            f4 q1 = __builtin_nontemporal_load(rbase + k + 1 * 64);
            f4 q2 = __builtin_nontemporal_load(rbase + k + 2 * 64);
            f4 q3 = __builtin_nontemporal_load(rbase + k + 3 * 64);
            i4 l0 = ll[k + 0 * 64];
            i4 l1 = ll[k + 1 * 64];
            i4 l2 = ll[k + 2 * 64];
            i4 l3 = ll[k + 3 * 64];
            s += aff_term(q0, l0, ln);
            s += aff_term(q1, l1, ln);
            s += aff_term(q2, l2, ln);
            s += aff_term(q3, l3, ln);
        }
        s = block_reduce_f(s, sm);
        if (tid == 0) aff_part[grp] = s;
    } else {
        // ---------------- weighted CE on 256 full-res pixels ----------------
        const int grp = bid >> 1;              // 0..2303
        const int idx = grp * 256 + threadIdx.x;
        float num1 = 0.f, num2 = 0.f, den = 0.f;

        const int h = idx / FULL_H, w = idx - h * FULL_H;
        const int t = target[idx];
        if (t != IGN) {
            // half-pixel bilinear src coords, scale = 96/768 = 0.125, edge-clamped
            float py = (h + 0.5f) * 0.125f - 0.5f;
            float px = (w + 0.5f) * 0.125f - 0.5f;
            int y0 = (int)floorf(py); float fy = py - (float)y0;
            int x0 = (int)floorf(px); float fx = px - (float)x0;
            int y1 = min(y0 + 1, PH - 1); y0 = max(y0, 0);
            int x1 = min(x0 + 1, PH - 1); x0 = max(x0, 0);
            const float w00 = (1.f - fx) * (1.f - fy), w10 = fx * (1.f - fy);
            const float w01 = (1.f - fx) * fy,         w11 = fx * fy;
            const int o00 = y0 * PH + x0, o10 = y0 * PH + x1;
            const int o01 = y1 * PH + x0, o11 = y1 * PH + x1;

            float se1 = 0.f, se2 = 0.f, vt1 = 0.f, vt2 = 0.f;
            #pragma unroll
            for (int c = 0; c < NC; ++c) {
                const float* b1 = lg1 + c * NPIX;
                const float* b2 = lg2 + c * NPIX;
                float v1 = w00 * b1[o00] + w10 * b1[o10] + w01 * b1[o01] + w11 * b1[o11];
                float v2 = w00 * b2[o00] + w10 * b2[o10] + w01 * b2[o01] + w11 * b2[o11];
                se1 += __expf(v1);
                se2 += __expf(v2);
                if (c == t) { vt1 = v1; vt2 = v2; }
            }
            const float wt = cw[t];
            num1 = wt * (__logf(se1) - vt1);
            num2 = wt * (__logf(se2) - vt2);
            den  = wt;
        }

        float r1 = block_reduce_f(num1, sm); __syncthreads();
        float r2 = block_reduce_f(num2, sm); __syncthreads();
        float rd = block_reduce_f(den,  sm);
        if (threadIdx.x == 0) {
            p1[grp] = r1;
            p2[grp] = r2;
            pd[grp] = rd;
        }
    }
}

__global__ __launch_bounds__(256) void final_kernel(const float* __restrict__ aff_part,
                                                    const float* __restrict__ p1,
                                                    const float* __restrict__ p2,
                                                    const float* __restrict__ pd,
                                                    float* __restrict__ out) {
    __shared__ double sm[4];
    double sa = 0.0, s1 = 0.0, s2 = 0.0, sd = 0.0;
    for (int i = threadIdx.x; i < AFF_BLOCKS; i += 256) sa += (double)aff_part[i];
    for (int i = threadIdx.x; i < CE_BLOCKS; i += 256) {
        s1 += (double)p1[i];
        s2 += (double)p2[i];
        sd += (double)pd[i];
    }
    double ra = block_reduce_d(sa, sm); __syncthreads();
    double r1 = block_reduce_d(s1, sm); __syncthreads();
    double r2 = block_reduce_d(s2, sm); __syncthreads();
    double rd = block_reduce_d(sd, sm);
    if (threadIdx.x == 0) {
        double aff = ra / ((double)NPIX * (double)NPIX);
        double l1  = r1 / rd;
        double l2  = r2 / rd;
        out[0] = (float)(0.4 * l1 + l2 + 1.0 * aff);
    }
}

extern "C" void kernel_launch(void* const* d_in, const int* in_sizes, int n_in,
                              void* d_out, int out_size, void* d_ws, size_t ws_size,
                              hipStream_t stream) {
    const float* aff_pred = (const float*)d_in[0];
    const float* logits1  = (const float*)d_in[1];
    const float* logits2  = (const float*)d_in[2];
    const float* cw       = (const float*)d_in[3];
    const int*   target   = (const int*)d_in[4];
    float* out = (float*)d_out;

    char* ws = (char*)d_ws;
    int*   lab      = (int*)ws;
    float* aff_part = (float*)(ws + 36864);
    float* ce1      = (float*)(ws + 46080);
    float* ce2      = (float*)(ws + 55296);
    float* ced      = (float*)(ws + 64512);

    prep_kernel<<<(NPIX + 255) / 256, 256, 0, stream>>>(target, lab);
    fused_kernel<<<FUSED_BLOCKS, 256, 0, stream>>>(aff_pred, lab, logits1, logits2, cw,
                                                   target, aff_part, ce1, ce2, ced);
    final_kernel<<<1, 256, 0, stream>>>(aff_part, ce1, ce2, ced, out);
}

// Round 11
// 99.214 us; speedup vs baseline: 1.0076x; 1.0076x over previous
//
#include <hip/hip_runtime.h>
#include <math.h>

#define NPIX   9216        // 96*96
#define PH     96
#define FULL_H 768
#define NC     19
#define IGN    255

#define AFF_ROWS   4                          // one row per wave
#define AFF_BLOCKS (NPIX / AFF_ROWS)          // 2304
#define CE_BLOCKS  ((FULL_H * FULL_H) / 256)  // 2304

typedef float f4 __attribute__((ext_vector_type(4)));
typedef int   i4 __attribute__((ext_vector_type(4)));

// ws layout (bytes):
//   aff_part float[AFF_BLOCKS]    @ 0
//   ce1_part float[CE_BLOCKS]     @ 9216
//   ce2_part float[CE_BLOCKS]     @ 18432
//   ced_part float[CE_BLOCKS]     @ 27648

__device__ __forceinline__ float block_reduce_f(float v, float* sm) {
    #pragma unroll
    for (int o = 32; o > 0; o >>= 1) v += __shfl_down(v, o, 64);
    int lane = threadIdx.x & 63, wid = threadIdx.x >> 6;
    if (lane == 0) sm[wid] = v;
    __syncthreads();
    if (threadIdx.x == 0) v = sm[0] + sm[1] + sm[2] + sm[3];
    return v;  // valid only in thread 0
}

__device__ __forceinline__ double block_reduce_d(double v, double* sm) {
    #pragma unroll
    for (int o = 32; o > 0; o >>= 1) v += __shfl_down(v, o, 64);
    int lane = threadIdx.x & 63, wid = threadIdx.x >> 6;
    if (lane == 0) sm[wid] = v;
    __syncthreads();
    if (threadIdx.x == 0) v = sm[0] + sm[1] + sm[2] + sm[3];
    return v;  // valid only in thread 0
}

__device__ __forceinline__ float aff_term(f4 p, i4 l, int ln) {
    float d0 = p.x - (l.x == ln ? 1.f : 0.f);
    float d1 = p.y - (l.y == ln ? 1.f : 0.f);
    float d2 = p.z - (l.z == ln ? 1.f : 0.f);
    float d3 = p.w - (l.w == ln ? 1.f : 0.f);
    return d0 * d0 + d1 * d1 + d2 * d2 + d3 * d3;
}

// Self-contained aff kernel: each block gathers the downsampled label table
// (lab[i] = target[(i/96)*8*768 + (i%96)*8]) into LDS itself (36 scalar
// L2-hit gathers per thread), then streams its 4 rows with NON-TEMPORAL
// 4x1KB bursts. No prep kernel, no global lab array, no dependency stall.
__global__ __launch_bounds__(256) void aff_kernel(const float* __restrict__ aff,
                                                  const int* __restrict__ target,
                                                  float* __restrict__ part) {
    __shared__ __align__(16) int slab[NPIX];   // 36 KB
    __shared__ float sm[4];

    const int tid = threadIdx.x;
    #pragma unroll
    for (int j = 0; j < NPIX / 256; ++j) {     // 36 iterations
        const int i = tid + j * 256;
        const int r = i / PH, c = i - r * PH;  // nearest: src = dst*8
        slab[i] = target[(r * 8) * FULL_H + c * 8];
    }
    __syncthreads();

    const int w    = tid >> 6;
    const int lane = tid & 63;
    const int row  = blockIdx.x * AFF_ROWS + w;
    const int ln   = slab[row];
    const f4* rbase = (const f4*)(aff + (size_t)row * NPIX);
    const i4* sl    = (const i4*)slab;

    float s = 0.f;
    #pragma unroll
    for (int i = 0; i < 9; ++i) {
        const int k = i * 256 + lane;          // f4 index within row
        f4 q0 = __builtin_nontemporal_load(rbase + k + 0 * 64);
        f4 q1 = __builtin_nontemporal_load(rbase + k + 1 * 64);
        f4 q2 = __builtin_nontemporal_load(rbase + k + 2 * 64);
        f4 q3 = __builtin_nontemporal_load(rbase + k + 3 * 64);
        i4 l0 = sl[k + 0 * 64];
        i4 l1 = sl[k + 1 * 64];
        i4 l2 = sl[k + 2 * 64];
        i4 l3 = sl[k + 3 * 64];
        s += aff_term(q0, l0, ln);
        s += aff_term(q1, l1, ln);
        s += aff_term(q2, l2, ln);
        s += aff_term(q3, l3, ln);
    }
    s = block_reduce_f(s, sm);
    if (tid == 0) part[blockIdx.x] = s;
}

__global__ __launch_bounds__(256) void ce_kernel(const float* __restrict__ lg1,
                                                 const float* __restrict__ lg2,
                                                 const float* __restrict__ cw,
                                                 const int* __restrict__ target,
                                                 float* __restrict__ p1,
                                                 float* __restrict__ p2,
                                                 float* __restrict__ pd) {
    __shared__ float sm[4];
    const int idx = blockIdx.x * 256 + threadIdx.x;   // 768*768 = 2304 blocks exactly
    float num1 = 0.f, num2 = 0.f, den = 0.f;

    const int h = idx / FULL_H, w = idx - h * FULL_H;
    const int t = target[idx];
    if (t != IGN) {
        // half-pixel bilinear src coords, scale = 96/768 = 0.125, edge-clamped
        float py = (h + 0.5f) * 0.125f - 0.5f;
        float px = (w + 0.5f) * 0.125f - 0.5f;
        int y0 = (int)floorf(py); float fy = py - (float)y0;
        int x0 = (int)floorf(px); float fx = px - (float)x0;
        int y1 = min(y0 + 1, PH - 1); y0 = max(y0, 0);
        int x1 = min(x0 + 1, PH - 1); x0 = max(x0, 0);
        const float w00 = (1.f - fx) * (1.f - fy), w10 = fx * (1.f - fy);
        const float w01 = (1.f - fx) * fy,         w11 = fx * fy;
        const int o00 = y0 * PH + x0, o10 = y0 * PH + x1;
        const int o01 = y1 * PH + x0, o11 = y1 * PH + x1;

        float se1 = 0.f, se2 = 0.f, vt1 = 0.f, vt2 = 0.f;
        #pragma unroll
        for (int c = 0; c < NC; ++c) {
            const float* b1 = lg1 + c * NPIX;
            const float* b2 = lg2 + c * NPIX;
            float v1 = w00 * b1[o00] + w10 * b1[o10] + w01 * b1[o01] + w11 * b1[o11];
            float v2 = w00 * b2[o00] + w10 * b2[o10] + w01 * b2[o01] + w11 * b2[o11];
            se1 += __expf(v1);
            se2 += __expf(v2);
            if (c == t) { vt1 = v1; vt2 = v2; }
        }
        const float wt = cw[t];
        num1 = wt * (__logf(se1) - vt1);
        num2 = wt * (__logf(se2) - vt2);
        den  = wt;
    }

    float r1 = block_reduce_f(num1, sm); __syncthreads();
    float r2 = block_reduce_f(num2, sm); __syncthreads();
    float rd = block_reduce_f(den,  sm);
    if (threadIdx.x == 0) {
        p1[blockIdx.x] = r1;
        p2[blockIdx.x] = r2;
        pd[blockIdx.x] = rd;
    }
}

__global__ __launch_bounds__(256) void final_kernel(const float* __restrict__ aff_part,
                                                    const float* __restrict__ p1,
                                                    const float* __restrict__ p2,
                                                    const float* __restrict__ pd,
                                                    float* __restrict__ out) {
    __shared__ double sm[4];
    double sa = 0.0, s1 = 0.0, s2 = 0.0, sd = 0.0;
    for (int i = threadIdx.x; i < AFF_BLOCKS; i += 256) sa += (double)aff_part[i];
    for (int i = threadIdx.x; i < CE_BLOCKS; i += 256) {
        s1 += (double)p1[i];
        s2 += (double)p2[i];
        sd += (double)pd[i];
    }
    double ra = block_reduce_d(sa, sm); __syncthreads();
    double r1 = block_reduce_d(s1, sm); __syncthreads();
    double r2 = block_reduce_d(s2, sm); __syncthreads();
    double rd = block_reduce_d(sd, sm);
    if (threadIdx.x == 0) {
        double aff = ra / ((double)NPIX * (double)NPIX);
        double l1  = r1 / rd;
        double l2  = r2 / rd;
        out[0] = (float)(0.4 * l1 + l2 + 1.0 * aff);
    }
}

extern "C" void kernel_launch(void* const* d_in, const int* in_sizes, int n_in,
                              void* d_out, int out_size, void* d_ws, size_t ws_size,
                              hipStream_t stream) {
    const float* aff_pred = (const float*)d_in[0];
    const float* logits1  = (const float*)d_in[1];
    const float* logits2  = (const float*)d_in[2];
    const float* cw       = (const float*)d_in[3];
    const int*   target   = (const int*)d_in[4];
    float* out = (float*)d_out;

    char* ws = (char*)d_ws;
    float* aff_part = (float*)(ws + 0);
    float* ce1      = (float*)(ws +  9216);
    float* ce2      = (float*)(ws + 18432);
    float* ced      = (float*)(ws + 27648);

    aff_kernel<<<AFF_BLOCKS, 256, 0, stream>>>(aff_pred, target, aff_part);
    ce_kernel<<<CE_BLOCKS, 256, 0, stream>>>(logits1, logits2, cw, target, ce1, ce2, ced);
    final_kernel<<<1, 256, 0, stream>>>(aff_part, ce1, ce2, ced, out);
}

// Round 12
// 80.637 us; speedup vs baseline: 1.2397x; 1.2304x over previous
//
#include <hip/hip_runtime.h>
#include <math.h>

#define NPIX   9216        // 96*96
#define PH     96
#define FULL_H 768
#define NC     19
#define IGN    255

#define AFF_ROWS   4                          // one row per wave
#define AFF_BLOCKS (NPIX / AFF_ROWS)          // 2304
#define CE_BLOCKS  ((FULL_H * FULL_H) / 256)  // 2304

typedef float f4 __attribute__((ext_vector_type(4)));
typedef int   i4 __attribute__((ext_vector_type(4)));

// ws layout (bytes):
//   lab      int[9216]            @ 0
//   aff_part float[AFF_BLOCKS]    @ 36864
//   ce1_part float[CE_BLOCKS]     @ 46080
//   ce2_part float[CE_BLOCKS]     @ 55296
//   ced_part float[CE_BLOCKS]     @ 64512

__device__ __forceinline__ float block_reduce_f(float v, float* sm) {
    #pragma unroll
    for (int o = 32; o > 0; o >>= 1) v += __shfl_down(v, o, 64);
    int lane = threadIdx.x & 63, wid = threadIdx.x >> 6;
    if (lane == 0) sm[wid] = v;
    __syncthreads();
    if (threadIdx.x == 0) v = sm[0] + sm[1] + sm[2] + sm[3];
    return v;  // valid only in thread 0
}

__device__ __forceinline__ double block_reduce_d(double v, double* sm) {
    #pragma unroll
    for (int o = 32; o > 0; o >>= 1) v += __shfl_down(v, o, 64);
    int lane = threadIdx.x & 63, wid = threadIdx.x >> 6;
    if (lane == 0) sm[wid] = v;
    __syncthreads();
    if (threadIdx.x == 0) v = sm[0] + sm[1] + sm[2] + sm[3];
    return v;  // valid only in thread 0
}

__global__ __launch_bounds__(256) void prep_kernel(const int* __restrict__ target,
                                                   int* __restrict__ lab) {
    int i = blockIdx.x * 256 + threadIdx.x;
    if (i < NPIX) {
        int r = i / PH, c = i % PH;   // nearest: src = floor(dst*768/96) = dst*8
        lab[i] = target[(r * 8) * FULL_H + c * 8];
    }
}

__device__ __forceinline__ float aff_term(f4 p, i4 l, int ln) {
    float d0 = p.x - (l.x == ln ? 1.f : 0.f);
    float d1 = p.y - (l.y == ln ? 1.f : 0.f);
    float d2 = p.z - (l.z == ln ? 1.f : 0.f);
    float d3 = p.w - (l.w == ln ? 1.f : 0.f);
    return d0 * d0 + d1 * d1 + d2 * d2 + d3 * d3;
}

// One wave = one row, read strictly sequentially in 4x1KB bursts (4KB/iter).
// Stream loads are NON-TEMPORAL (nt): no L1/L2 allocation for zero-reuse data.
// lab staged in LDS so the global stream is the ONLY L1/HBM traffic.
__global__ __launch_bounds__(256) void aff_kernel(const float* __restrict__ aff,
                                                  const int* __restrict__ lab,
                                                  float* __restrict__ part) {
    __shared__ __align__(16) int slab[NPIX];   // 36 KB
    __shared__ float sm[4];

    const int tid = threadIdx.x;
    // stage lab -> LDS (coalesced int4)
    const i4* lp = (const i4*)lab;
    i4* sp = (i4*)slab;
    #pragma unroll
    for (int j = 0; j < 9; ++j) sp[tid + j * 256] = lp[tid + j * 256];
    __syncthreads();

    const int w    = tid >> 6;
    const int lane = tid & 63;
    const int row  = blockIdx.x * AFF_ROWS + w;
    const int ln   = slab[row];
    const f4* rbase = (const f4*)(aff + (size_t)row * NPIX);
    const i4* sl    = (const i4*)slab;

    float s = 0.f;
    #pragma unroll
    for (int i = 0; i < 9; ++i) {
        const int k = i * 256 + lane;          // f4 index within row
        f4 q0 = __builtin_nontemporal_load(rbase + k + 0 * 64);
        f4 q1 = __builtin_nontemporal_load(rbase + k + 1 * 64);
        f4 q2 = __builtin_nontemporal_load(rbase + k + 2 * 64);
        f4 q3 = __builtin_nontemporal_load(rbase + k + 3 * 64);
        i4 l0 = sl[k + 0 * 64];
        i4 l1 = sl[k + 1 * 64];
        i4 l2 = sl[k + 2 * 64];
        i4 l3 = sl[k + 3 * 64];
        s += aff_term(q0, l0, ln);
        s += aff_term(q1, l1, ln);
        s += aff_term(q2, l2, ln);
        s += aff_term(q3, l3, ln);
    }
    s = block_reduce_f(s, sm);
    if (tid == 0) part[blockIdx.x] = s;
}

__global__ __launch_bounds__(256) void ce_kernel(const float* __restrict__ lg1,
                                                 const float* __restrict__ lg2,
                                                 const float* __restrict__ cw,
                                                 const int* __restrict__ target,
                                                 float* __restrict__ p1,
                                                 float* __restrict__ p2,
                                                 float* __restrict__ pd) {
    __shared__ float sm[4];
    const int idx = blockIdx.x * 256 + threadIdx.x;   // 768*768 = 2304 blocks exactly
    float num1 = 0.f, num2 = 0.f, den = 0.f;

    const int h = idx / FULL_H, w = idx - h * FULL_H;
    const int t = target[idx];
    if (t != IGN) {
        // half-pixel bilinear src coords, scale = 96/768 = 0.125, edge-clamped
        float py = (h + 0.5f) * 0.125f - 0.5f;
        float px = (w + 0.5f) * 0.125f - 0.5f;
        int y0 = (int)floorf(py); float fy = py - (float)y0;
        int x0 = (int)floorf(px); float fx = px - (float)x0;
        int y1 = min(y0 + 1, PH - 1); y0 = max(y0, 0);
        int x1 = min(x0 + 1, PH - 1); x0 = max(x0, 0);
        const float w00 = (1.f - fx) * (1.f - fy), w10 = fx * (1.f - fy);
        const float w01 = (1.f - fx) * fy,         w11 = fx * fy;
        const int o00 = y0 * PH + x0, o10 = y0 * PH + x1;
        const int o01 = y1 * PH + x0, o11 = y1 * PH + x1;

        float se1 = 0.f, se2 = 0.f, vt1 = 0.f, vt2 = 0.f;
        #pragma unroll
        for (int c = 0; c < NC; ++c) {
            const float* b1 = lg1 + c * NPIX;
            const float* b2 = lg2 + c * NPIX;
            float v1 = w00 * b1[o00] + w10 * b1[o10] + w01 * b1[o01] + w11 * b1[o11];
            float v2 = w00 * b2[o00] + w10 * b2[o10] + w01 * b2[o01] + w11 * b2[o11];
            se1 += __expf(v1);
            se2 += __expf(v2);
            if (c == t) { vt1 = v1; vt2 = v2; }
        }
        const float wt = cw[t];
        num1 = wt * (__logf(se1) - vt1);
        num2 = wt * (__logf(se2) - vt2);
        den  = wt;
    }

    float r1 = block_reduce_f(num1, sm); __syncthreads();
    float r2 = block_reduce_f(num2, sm); __syncthreads();
    float rd = block_reduce_f(den,  sm);
    if (threadIdx.x == 0) {
        p1[blockIdx.x] = r1;
        p2[blockIdx.x] = r2;
        pd[blockIdx.x] = rd;
    }
}

__global__ __launch_bounds__(256) void final_kernel(const float* __restrict__ aff_part,
                                                    const float* __restrict__ p1,
                                                    const float* __restrict__ p2,
                                                    const float* __restrict__ pd,
                                                    float* __restrict__ out) {
    __shared__ double sm[4];
    double sa = 0.0, s1 = 0.0, s2 = 0.0, sd = 0.0;
    for (int i = threadIdx.x; i < AFF_BLOCKS; i += 256) sa += (double)aff_part[i];
    for (int i = threadIdx.x; i < CE_BLOCKS; i += 256) {
        s1 += (double)p1[i];
        s2 += (double)p2[i];
        sd += (double)pd[i];
    }
    double ra = block_reduce_d(sa, sm); __syncthreads();
    double r1 = block_reduce_d(s1, sm); __syncthreads();
    double r2 = block_reduce_d(s2, sm); __syncthreads();
    double rd = block_reduce_d(sd, sm);
    if (threadIdx.x == 0) {
        double aff = ra / ((double)NPIX * (double)NPIX);
        double l1  = r1 / rd;
        double l2  = r2 / rd;
        out[0] = (float)(0.4 * l1 + l2 + 1.0 * aff);
    }
}

extern "C" void kernel_launch(void* const* d_in, const int* in_sizes, int n_in,
                              void* d_out, int out_size, void* d_ws, size_t ws_size,
                              hipStream_t stream) {
    const float* aff_pred = (const float*)d_in[0];
    const float* logits1  = (const float*)d_in[1];
    const float* logits2  = (const float*)d_in[2];
    const float* cw       = (const float*)d_in[3];
    const int*   target   = (const int*)d_in[4];
    float* out = (float*)d_out;

    char* ws = (char*)d_ws;
    int*   lab      = (int*)ws;
    float* aff_part = (float*)(ws + 36864);
    float* ce1      = (float*)(ws + 46080);
    float* ce2      = (float*)(ws + 55296);
    float* ced      = (float*)(ws + 64512);

    prep_kernel<<<(NPIX + 255) / 256, 256, 0, stream>>>(target, lab);
    aff_kernel<<<AFF_BLOCKS, 256, 0, stream>>>(aff_pred, lab, aff_part);
    ce_kernel<<<CE_BLOCKS, 256, 0, stream>>>(logits1, logits2, cw, target, ce1, ce2, ced);
    final_kernel<<<1, 256, 0, stream>>>(aff_part, ce1, ce2, ced, out);
}